// Round 11
// baseline (125.871 us; speedup 1.0000x reference)
//
#include <hip/hip_runtime.h>
#include <hip/hip_bf16.h>

// DirectionalSeparableConv2D — round 11: fused kernel, conflict + overlap fix.
// r10 = 103us vs 41us memory floor. Diagnosis: (a) 1.38e7 LDS bank conflicts
// (~22us): xs row stride 64 dwords ≡ 0 mod 32 -> dwconv taps all land on
// col%32 banks; yT XOR-swizzle made transpose WRITES 8-way. (b) chunk DMA
// only overlapped the short transpose phase.
// Fixes: xs rows padded to 17 quads (stride ≡ 4 mod 32, dead quad fed from
// zb to keep the DMA dest linear); yT padded [p][136] (writes 32-bank
// distinct with lane=channel transpose, reads balanced, 16B aligned); ycp
// padded [8][392]; xs double-buffered (CHK=8) with stage(t+1) issued BEFORE
// dwconv(t). LDS 162944 B.

namespace {
constexpr int HH = 48, WW = 48, HW = HH * WW;
constexpr int C_IN = 128, C_OUT = 128, NB = 128;
constexpr int RPB = 8;                  // stripe rows per block
constexpr int NSTR = HH / RPB;          // 6
constexpr int PIX = RPB * WW;           // 384
constexpr int NT = 512;
constexpr int CHK = 8;                  // channels per chunk
constexpr int NCHK = C_IN / CHK;        // 16
constexpr int XR = RPB + 4;             // 12 staged rows
constexpr int QR = 17;                  // quads per staged row (16 data + 1 pad)
constexpr int XQ = CHK * XR * QR;       // 1632 quads per buffer
constexpr int YTS = 136;                // yT row stride (ushorts), 272B = 17*16
constexpr int YCS = 392;                // ycp row stride (ushorts)
constexpr size_t M_BYTES = 128 * 128 * 2;
constexpr size_t ZB_OFF = M_BYTES;
}

typedef __attribute__((ext_vector_type(8))) short bf16x8;
typedef __attribute__((ext_vector_type(4))) float f32x4;

__device__ __forceinline__ ushort f2bf(float f) {
    __hip_bfloat16 h = __float2bfloat16(f);
    return *reinterpret_cast<ushort*>(&h);
}

// ======================= k0: build M_bf[o][c] (bf16) =======================
__global__ void build_M(const float* __restrict__ c2c, const float* __restrict__ p2c,
                        const float* __restrict__ d2c, const float* __restrict__ c2d,
                        const float* __restrict__ d2dW, ushort* __restrict__ Mbf) {
    int t = blockIdx.x * 256 + threadIdx.x;
    if (t >= 128 * 128) return;
    int o = t & 127, c = t >> 7;
    float v;
    if (o < 32) {
        if (c < 32)       v = c2c[o * 32 + c];
        else if (c < 56)  v = p2c[o * 24 + c - 32];
        else if (c < 80)  v = p2c[o * 24 + c - 56];
        else if (c < 104) v = d2c[o * 24 + c - 80];
        else              v = d2c[o * 24 + c - 104];
    } else {
        int g = (o - 32) / 24, oo = (o - 32) % 24;
        if (c < 32) v = c2d[oo * 32 + c];
        else {
            int gc = (c - 32) / 24, cc2 = (c - 32) % 24;
            v = (gc == g) ? d2dW[oo * 24 + cc2] : 0.f;
        }
    }
    Mbf[o * 128 + c] = f2bf(v);
}

// ======================= fused kernel =======================
__global__ __launch_bounds__(NT) void dsc_fused(
    const float* __restrict__ x,
    const float* __restrict__ cen_t,   // [32,3,3]
    const float* __restrict__ dir_t,   // [24,5]
    const ushort* __restrict__ Mbf,    // bf16 [128o][128c]
    const float* __restrict__ zb,      // 16B zero block
    float* __restrict__ out)
{
    __shared__ float  xs[2][XQ * 4];       // 2 x 26112 B; row = 17 quads
    __shared__ ushort yT[PIX * YTS];       // 104448 B
    __shared__ ushort ycp[CHK * YCS];      // 6272 B

    const int tid = threadIdx.x;
    const int b   = blockIdx.x / NSTR;
    const int h0  = (blockIdx.x % NSTR) * RPB;
    const float* __restrict__ xb = x + (size_t)b * C_IN * HW;

    // ---- stage chunk t into buffer buf: dest linear in quad index d ----
    auto stage = [&](int t, int buf) {
        const int c0 = t * CHK;
#pragma unroll
        for (int k = 0; k < 4; ++k) {          // 1632 quads / 512 thr
            int d = tid + k * NT;
            if (d < XQ) {
                int q  = d % QR;               // 0..16
                int cr = d / QR;               // 0..95
                int r  = cr % XR;
                int c  = cr / XR;
                int gh = h0 - 2 + r;
                bool ok = ((unsigned)gh < (unsigned)HH) && (q < 12);
                const float* src = ok ? (xb + (size_t)(c0 + c) * HW + gh * WW + q * 4) : zb;
                __builtin_amdgcn_global_load_lds(
                    (const __attribute__((address_space(1))) unsigned int*)src,
                    (__attribute__((address_space(3))) unsigned int*)(&xs[buf][0] + (size_t)d * 4),
                    16, 0, 0);
            }
        }
    };

    // ---- dwconv chunk t: 768 tasks (c,row,quad) -> ycp[c][p..p+3] ----
    auto dwconv = [&](int t, int buf) {
        const int c0 = t * CHK;
#pragma unroll
        for (int k = 0; k < 2; ++k) {
            int task = tid + k * NT;
            if (task >= CHK * 96) break;
            int c    = task / 96;
            int rem  = task % 96;
            int row  = rem / 12;
            int w0   = (rem % 12) * 4;
            int cc   = c0 + c;
            float o0 = 0.f, o1 = 0.f, o2 = 0.f, o3 = 0.f;
#define XROW(i_) (&xs[buf][(size_t)((c * XR + row + (i_)) * QR) * 4])
            if (cc < 32) {                      // 3x3
#pragma unroll
                for (int i = 0; i < 3; ++i) {
                    const float* xr = XROW(i + 1);
                    float v[6];
#pragma unroll
                    for (int j = 0; j < 6; ++j) v[j] = xr[(w0 + j - 1) & 63];
                    float k0 = cen_t[cc * 9 + i * 3 + 0];
                    float k1 = cen_t[cc * 9 + i * 3 + 1];
                    float k2 = cen_t[cc * 9 + i * 3 + 2];
                    o0 += k0 * v[0] + k1 * v[1] + k2 * v[2];
                    o1 += k0 * v[1] + k1 * v[2] + k2 * v[3];
                    o2 += k0 * v[2] + k1 * v[3] + k2 * v[4];
                    o3 += k0 * v[3] + k1 * v[4] + k2 * v[5];
                }
            } else if (cc < 56) {               // horizontal 1x5
                int cd = cc - 32;
                const float* xr = XROW(2);
                float v[8];
#pragma unroll
                for (int j = 0; j < 8; ++j) v[j] = xr[(w0 + j - 2) & 63];
#pragma unroll
                for (int i = 0; i < 5; ++i) {
                    float tt = dir_t[cd * 5 + i];
                    o0 += tt * v[i]; o1 += tt * v[i + 1]; o2 += tt * v[i + 2]; o3 += tt * v[i + 3];
                }
            } else if (cc < 80) {               // vertical 5x1
                int cd = cc - 56;
#pragma unroll
                for (int i = 0; i < 5; ++i) {
                    float tt = dir_t[cd * 5 + i];
                    float4 vq = *(const float4*)&XROW(i)[w0];
                    o0 += tt * vq.x; o1 += tt * vq.y; o2 += tt * vq.z; o3 += tt * vq.w;
                }
            } else if (cc < 104) {              // diag x[h+i-2][w+i-2]
                int cd = cc - 80;
#pragma unroll
                for (int i = 0; i < 5; ++i) {
                    float tt = dir_t[cd * 5 + i];
                    const float* xr = XROW(i);
                    int base = w0 + i - 2;
                    o0 += tt * xr[(base + 0) & 63];
                    o1 += tt * xr[(base + 1) & 63];
                    o2 += tt * xr[(base + 2) & 63];
                    o3 += tt * xr[(base + 3) & 63];
                }
            } else {                            // anti-diag x[h+i-2][w+2-i]
                int cd = cc - 104;
#pragma unroll
                for (int i = 0; i < 5; ++i) {
                    float tt = dir_t[cd * 5 + i];
                    const float* xr = XROW(i);
                    int base = w0 + 2 - i;
                    o0 += tt * xr[(base + 0) & 63];
                    o1 += tt * xr[(base + 1) & 63];
                    o2 += tt * xr[(base + 2) & 63];
                    o3 += tt * xr[(base + 3) & 63];
                }
            }
#undef XROW
            int p = row * 48 + w0;
            ushort4 s = {f2bf(o0), f2bf(o1), f2bf(o2), f2bf(o3)};
            *(ushort4*)&ycp[c * YCS + p] = s;
        }
    };

    // ---- transpose chunk t: ycp[c][p] -> yT[p][c0+c], lane = channel ----
    auto transpose = [&](int t) {
        const int c0 = t * CHK;
        const int c  = tid & 7;
        const int pp = tid >> 3;                // 0..63
#pragma unroll
        for (int j = 0; j < 6; ++j) {
            int p = pp + 64 * j;
            yT[p * YTS + c0 + c] = ycp[c * YCS + p];
        }
    };

    // ================= channel-streamed dwconv =================
    stage(0, 0);
    __syncthreads();
    for (int t = 0; t < NCHK; ++t) {
        if (t + 1 < NCHK) stage(t + 1, (t + 1) & 1);   // DMA overlaps dwconv
        dwconv(t, t & 1);
        __syncthreads();                                // ycp ready (+DMA drain)
        transpose(t);
        __syncthreads();                                // ycp free for next chunk
    }

    // ================= MFMA mix: 2 passes x 64 out-ch =================
    const int l     = tid & 63;
    const int wv    = tid >> 6;                 // 0..7
    const int ofr   = wv & 3;
    const int phalf = wv >> 2;
    float* __restrict__ ob = out + (size_t)b * C_OUT * HW + h0 * WW;

#pragma unroll
    for (int pass = 0; pass < 2; ++pass) {
        int o0 = pass * 64 + ofr * 16;
        bf16x8 afr[4];
#pragma unroll
        for (int kb = 0; kb < 4; ++kb)
            afr[kb] = *(const bf16x8*)(Mbf + (o0 + (l & 15)) * 128 + kb * 32 + (l >> 4) * 8);
        f32x4 acc[12] = {};
#pragma unroll
        for (int kb = 0; kb < 4; ++kb)
#pragma unroll
            for (int pf = 0; pf < 12; ++pf) {
                int p = (phalf * 12 + pf) * 16 + (l & 15);
                bf16x8 bfr = *(const bf16x8*)&yT[p * YTS + kb * 32 + (l >> 4) * 8];
                acc[pf] = __builtin_amdgcn_mfma_f32_16x16x32_bf16(afr[kb], bfr, acc[pf], 0, 0, 0);
            }
#pragma unroll
        for (int pf = 0; pf < 12; ++pf) {
            int p = (phalf * 12 + pf) * 16 + (l & 15);
            int obase = o0 + (l >> 4) * 4;
#pragma unroll
            for (int r = 0; r < 4; ++r)
                ob[(size_t)(obase + r) * HW + p] = acc[pf][r];
        }
    }
}

// ======================= launcher =======================
extern "C" void kernel_launch(void* const* d_in, const int* in_sizes, int n_in,
                              void* d_out, int out_size, void* d_ws, size_t ws_size,
                              hipStream_t stream) {
    const float* x     = (const float*)d_in[0];
    const float* cen_t = (const float*)d_in[1];
    const float* dir_t = (const float*)d_in[2];
    const float* c2c   = (const float*)d_in[3];
    const float* p2c   = (const float*)d_in[4];
    const float* d2c   = (const float*)d_in[5];
    const float* c2d   = (const float*)d_in[6];
    const float* d2dW  = (const float*)d_in[7];
    float* out = (float*)d_out;

    ushort* Mbf = (ushort*)d_ws;                       // 32 KiB
    float*  zb  = (float*)((char*)d_ws + ZB_OFF);      // 16 B zero block

    hipMemsetAsync(zb, 0, 64, stream);                 // ws is poisoned each run
    build_M<<<64, 256, 0, stream>>>(c2c, p2c, d2c, c2d, d2dW, Mbf);
    dsc_fused<<<NB * NSTR, NT, 0, stream>>>(x, cen_t, dir_t, Mbf, zb, out);
}

// Round 12
// 117.479 us; speedup vs baseline: 1.0714x; 1.0714x over previous
//
#include <hip/hip_runtime.h>
#include <hip/hip_bf16.h>

// DirectionalSeparableConv2D — round 12: kill LDS bank conflicts for real.
// r10/r11 analysis error: dwconv taps are quad-aligned (w0 mult of 4, row
// strides ≡ 0/4 mod 32) -> every tap in bank-residue (j-1) mod 4 -> 8-way.
// b128 MFMA reads conflict at 16B bank-quad granularity and were fine.
// Fixes: (1) dwconv = 2-pixel tasks, lane-consecutive columns -> <=2-way
// (free); (2) ycp ushort2 writes lane-consecutive; (3) yT[384][128] with
// granule-XOR swizzle (g ^= p&7) on transpose-write and MFMA-read ->
// conflict-free both sides, saves 6KB -> ycp double-buffered -> transpose
// merged into dwconv phase -> 17 barriers (was 32). DMA still issued ahead.

namespace {
constexpr int HH = 48, WW = 48, HW = HH * WW;
constexpr int C_IN = 128, C_OUT = 128, NB = 128;
constexpr int RPB = 8;                  // stripe rows per block
constexpr int NSTR = HH / RPB;          // 6
constexpr int PIX = RPB * WW;           // 384
constexpr int NT = 512;
constexpr int CHK = 8;                  // channels per chunk
constexpr int NCHK = C_IN / CHK;        // 16
constexpr int XR = RPB + 4;             // 12 staged rows
constexpr int QR = 17;                  // quads per staged row
constexpr int XQ = CHK * XR * QR;       // 1632 quads per buffer
constexpr int XROWF = QR * 4;           // 68 floats per row
constexpr int YCS = 392;                // ycp row stride (ushorts)
constexpr size_t M_BYTES = 128 * 128 * 2;
constexpr size_t ZB_OFF = M_BYTES;
}

typedef __attribute__((ext_vector_type(8))) short bf16x8;
typedef __attribute__((ext_vector_type(4))) float f32x4;

__device__ __forceinline__ ushort f2bf(float f) {
    __hip_bfloat16 h = __float2bfloat16(f);
    return *reinterpret_cast<ushort*>(&h);
}

// ======================= k0: build M_bf[o][c] (bf16) =======================
__global__ void build_M(const float* __restrict__ c2c, const float* __restrict__ p2c,
                        const float* __restrict__ d2c, const float* __restrict__ c2d,
                        const float* __restrict__ d2dW, ushort* __restrict__ Mbf) {
    int t = blockIdx.x * 256 + threadIdx.x;
    if (t >= 128 * 128) return;
    int o = t & 127, c = t >> 7;
    float v;
    if (o < 32) {
        if (c < 32)       v = c2c[o * 32 + c];
        else if (c < 56)  v = p2c[o * 24 + c - 32];
        else if (c < 80)  v = p2c[o * 24 + c - 56];
        else if (c < 104) v = d2c[o * 24 + c - 80];
        else              v = d2c[o * 24 + c - 104];
    } else {
        int g = (o - 32) / 24, oo = (o - 32) % 24;
        if (c < 32) v = c2d[oo * 32 + c];
        else {
            int gc = (c - 32) / 24, cc2 = (c - 32) % 24;
            v = (gc == g) ? d2dW[oo * 24 + cc2] : 0.f;
        }
    }
    Mbf[o * 128 + c] = f2bf(v);
}

// ======================= fused kernel =======================
__global__ __launch_bounds__(NT) void dsc_fused(
    const float* __restrict__ x,
    const float* __restrict__ cen_t,   // [32,3,3]
    const float* __restrict__ dir_t,   // [24,5]
    const ushort* __restrict__ Mbf,    // bf16 [128o][128c]
    const float* __restrict__ zb,      // 16B zero block
    float* __restrict__ out)
{
    __shared__ float  xs[2][XQ * 4];        // 2 x 26112 B
    __shared__ ushort yT[PIX * 128];        // 98304 B, granule-XOR swizzled
    __shared__ ushort ycp[2][CHK * YCS];    // 2 x 6272 B   (total 163072)

    const int tid = threadIdx.x;
    const int b   = blockIdx.x / NSTR;
    const int h0  = (blockIdx.x % NSTR) * RPB;
    const float* __restrict__ xb = x + (size_t)b * C_IN * HW;

    // ---- stage chunk t into xs[buf]: dest linear in quad index ----
    auto stage = [&](int t, int buf) {
        const int c0 = t * CHK;
#pragma unroll
        for (int k = 0; k < 4; ++k) {
            int d = tid + k * NT;
            if (d < XQ) {
                int q  = d % QR;
                int cr = d / QR;
                int r  = cr % XR;
                int c  = cr / XR;
                int gh = h0 - 2 + r;
                bool ok = ((unsigned)gh < (unsigned)HH) && (q < 12);
                const float* src = ok ? (xb + (size_t)(c0 + c) * HW + gh * WW + q * 4) : zb;
                __builtin_amdgcn_global_load_lds(
                    (const __attribute__((address_space(1))) unsigned int*)src,
                    (__attribute__((address_space(3))) unsigned int*)(&xs[buf][0] + (size_t)d * 4),
                    16, 0, 0);
            }
        }
    };

    // ---- dwconv chunk t: 1536 two-pixel tasks -> ycp[t&1] ----
    auto dwconv = [&](int t) {
        const int c0 = t * CHK;
        const int buf = t & 1;
        ushort* yc = ycp[buf];
#pragma unroll
        for (int k = 0; k < 3; ++k) {
            int task = tid + k * NT;         // 0..1535
            int c   = task / 192;
            int pt  = task % 192;
            int row = pt / 24;
            int w0  = (pt % 24) * 2;         // even column
            int cc  = c0 + c;
            const float* xb0 = &xs[buf][(size_t)(c * XR) * XROWF];
            float a0 = 0.f, a1 = 0.f;
            if (cc < 32) {                   // 3x3: x[h+i-1][w+j-1]
#pragma unroll
                for (int i = 0; i < 3; ++i) {
                    const float* xr = xb0 + (row + 1 + i) * XROWF;
                    float v0 = xr[(w0 - 1) & 63];
                    float v1 = xr[w0];
                    float v2 = xr[w0 + 1];
                    float v3 = xr[(w0 + 2) & 63];
                    float k0 = cen_t[cc * 9 + i * 3 + 0];
                    float k1 = cen_t[cc * 9 + i * 3 + 1];
                    float k2 = cen_t[cc * 9 + i * 3 + 2];
                    a0 += k0 * v0 + k1 * v1 + k2 * v2;
                    a1 += k0 * v1 + k1 * v2 + k2 * v3;
                }
            } else if (cc < 56) {            // h: x[h][w+i-2]
                int cd = cc - 32;
                const float* xr = xb0 + (row + 2) * XROWF;
                float v[6];
#pragma unroll
                for (int m = 0; m < 6; ++m) v[m] = xr[(w0 + m - 2) & 63];
#pragma unroll
                for (int i = 0; i < 5; ++i) {
                    float tt = dir_t[cd * 5 + i];
                    a0 += tt * v[i];
                    a1 += tt * v[i + 1];
                }
            } else if (cc < 80) {            // v: x[h+i-2][w]
                int cd = cc - 56;
#pragma unroll
                for (int i = 0; i < 5; ++i) {
                    float tt = dir_t[cd * 5 + i];
                    float2 vq = *(const float2*)(xb0 + (row + i) * XROWF + w0);
                    a0 += tt * vq.x;
                    a1 += tt * vq.y;
                }
            } else if (cc < 104) {           // d1: x[h+i-2][w+i-2]
                int cd = cc - 80;
#pragma unroll
                for (int i = 0; i < 5; ++i) {
                    float tt = dir_t[cd * 5 + i];
                    const float* xr = xb0 + (row + i) * XROWF;
                    a0 += tt * xr[(w0 + i - 2) & 63];
                    a1 += tt * xr[(w0 + i - 1) & 63];
                }
            } else {                         // d2: x[h+i-2][w+2-i]
                int cd = cc - 104;
#pragma unroll
                for (int i = 0; i < 5; ++i) {
                    float tt = dir_t[cd * 5 + i];
                    const float* xr = xb0 + (row + i) * XROWF;
                    a0 += tt * xr[(w0 + 2 - i) & 63];
                    a1 += tt * xr[(w0 + 3 - i) & 63];
                }
            }
            ushort2 s = {f2bf(a0), f2bf(a1)};
            *(ushort2*)&yc[c * YCS + pt * 2] = s;
        }
    };

    // ---- transpose chunk t: ycp[t&1][c][p] -> yT (granule-swizzled) ----
    auto transpose = [&](int t) {
        const ushort* src = ycp[t & 1];
#pragma unroll
        for (int k = 0; k < 3; ++k) {
            int task = tid + k * NT;         // 1536 = 4 cpair x 384 p
            int cp = task & 3;
            int p  = task >> 2;
            ushort2 s;
            s.x = src[(cp * 2 + 0) * YCS + p];
            s.y = src[(cp * 2 + 1) * YCS + p];
            int gsw = t ^ (p & 7);           // granule index of this chunk is t
            *(ushort2*)((char*)yT + p * 256 + (gsw << 4) + (cp << 2)) = s;
        }
    };

    // ================= channel-streamed dwconv =================
    stage(0, 0);
    __syncthreads();
    for (int t = 0; t < NCHK; ++t) {
        if (t + 1 < NCHK) stage(t + 1, (t + 1) & 1);  // DMA overlaps compute
        dwconv(t);
        if (t > 0) transpose(t - 1);
        __syncthreads();                               // drains DMA, publishes ycp
    }
    transpose(NCHK - 1);
    __syncthreads();

    // ================= MFMA mix: 2 passes x 64 out-ch =================
    const int l     = tid & 63;
    const int wv    = tid >> 6;              // 0..7
    const int ofr   = wv & 3;
    const int phalf = wv >> 2;
    float* __restrict__ ob = out + (size_t)b * C_OUT * HW + h0 * WW;

#pragma unroll
    for (int pass = 0; pass < 2; ++pass) {
        int o0 = pass * 64 + ofr * 16;
        bf16x8 afr[4];
#pragma unroll
        for (int kb = 0; kb < 4; ++kb)
            afr[kb] = *(const bf16x8*)(Mbf + (o0 + (l & 15)) * 128 + kb * 32 + (l >> 4) * 8);
        f32x4 acc[12] = {};
#pragma unroll
        for (int kb = 0; kb < 4; ++kb) {
            int g = kb * 4 + (l >> 4);       // granule of this lane's k-slice
#pragma unroll
            for (int pf = 0; pf < 12; ++pf) {
                int p = (phalf * 12 + pf) * 16 + (l & 15);
                const bf16x8 bfr = *(const bf16x8*)((const char*)yT + p * 256 + ((g ^ (p & 7)) << 4));
                acc[pf] = __builtin_amdgcn_mfma_f32_16x16x32_bf16(afr[kb], bfr, acc[pf], 0, 0, 0);
            }
        }
#pragma unroll
        for (int pf = 0; pf < 12; ++pf) {
            int p = (phalf * 12 + pf) * 16 + (l & 15);
            int obase = o0 + (l >> 4) * 4;
#pragma unroll
            for (int r = 0; r < 4; ++r)
                ob[(size_t)(obase + r) * HW + p] = acc[pf][r];
        }
    }
}

// ======================= launcher =======================
extern "C" void kernel_launch(void* const* d_in, const int* in_sizes, int n_in,
                              void* d_out, int out_size, void* d_ws, size_t ws_size,
                              hipStream_t stream) {
    const float* x     = (const float*)d_in[0];
    const float* cen_t = (const float*)d_in[1];
    const float* dir_t = (const float*)d_in[2];
    const float* c2c   = (const float*)d_in[3];
    const float* p2c   = (const float*)d_in[4];
    const float* d2c   = (const float*)d_in[5];
    const float* c2d   = (const float*)d_in[6];
    const float* d2dW  = (const float*)d_in[7];
    float* out = (float*)d_out;

    ushort* Mbf = (ushort*)d_ws;                       // 32 KiB
    float*  zb  = (float*)((char*)d_ws + ZB_OFF);      // 16 B zero block

    hipMemsetAsync(zb, 0, 64, stream);                 // ws is poisoned each run
    build_M<<<64, 256, 0, stream>>>(c2c, p2c, d2c, c2d, d2dW, Mbf);
    dsc_fused<<<NB * NSTR, NT, 0, stream>>>(x, cen_t, dir_t, Mbf, zb, out);
}

// Round 13
// 115.663 us; speedup vs baseline: 1.0883x; 1.0157x over previous
//
#include <hip/hip_runtime.h>
#include <hip/hip_bf16.h>

// DirectionalSeparableConv2D — round 13: occupancy x2 + last conflict fix.
// r12 = 117.5us, conflicts 1.585e7->8.6e6 but VALUBusy 16% / Occ 21%:
// 163KB LDS -> 1 block/CU, NT=512 -> 2 waves/SIMD -> all LDS/DMA latency
// exposed. Fixes:
//   * NT=1024 (16 waves/block, 4/SIMD) - same LDS footprint, 2x hiding.
//   * dwconv pixel pair (w, w+24): r12's adjacent even pair made every tap
//     column single-parity -> 16 banks -> 4-way. Half-row split gives
//     lane-stride-1 columns on both reads -> <=2-way (free).
// Everything else (granule-swizzled yT, DMA-ahead, merged transpose) as r12.

namespace {
constexpr int HH = 48, WW = 48, HW = HH * WW;
constexpr int C_IN = 128, C_OUT = 128, NB = 128;
constexpr int RPB = 8;                  // stripe rows per block
constexpr int NSTR = HH / RPB;          // 6
constexpr int PIX = RPB * WW;           // 384
constexpr int NT = 1024;
constexpr int CHK = 8;                  // channels per chunk
constexpr int NCHK = C_IN / CHK;        // 16
constexpr int XR = RPB + 4;             // 12 staged rows
constexpr int QR = 17;                  // quads per staged row
constexpr int XQ = CHK * XR * QR;       // 1632 quads per buffer
constexpr int XROWF = QR * 4;           // 68 floats per row
constexpr int YCS = 392;                // ycp row stride (ushorts)
constexpr size_t M_BYTES = 128 * 128 * 2;
constexpr size_t ZB_OFF = M_BYTES;
}

typedef __attribute__((ext_vector_type(8))) short bf16x8;
typedef __attribute__((ext_vector_type(4))) float f32x4;

__device__ __forceinline__ ushort f2bf(float f) {
    __hip_bfloat16 h = __float2bfloat16(f);
    return *reinterpret_cast<ushort*>(&h);
}

// ======================= k0: build M_bf[o][c] (bf16) =======================
__global__ void build_M(const float* __restrict__ c2c, const float* __restrict__ p2c,
                        const float* __restrict__ d2c, const float* __restrict__ c2d,
                        const float* __restrict__ d2dW, ushort* __restrict__ Mbf) {
    int t = blockIdx.x * 256 + threadIdx.x;
    if (t >= 128 * 128) return;
    int o = t & 127, c = t >> 7;
    float v;
    if (o < 32) {
        if (c < 32)       v = c2c[o * 32 + c];
        else if (c < 56)  v = p2c[o * 24 + c - 32];
        else if (c < 80)  v = p2c[o * 24 + c - 56];
        else if (c < 104) v = d2c[o * 24 + c - 80];
        else              v = d2c[o * 24 + c - 104];
    } else {
        int g = (o - 32) / 24, oo = (o - 32) % 24;
        if (c < 32) v = c2d[oo * 32 + c];
        else {
            int gc = (c - 32) / 24, cc2 = (c - 32) % 24;
            v = (gc == g) ? d2dW[oo * 24 + cc2] : 0.f;
        }
    }
    Mbf[o * 128 + c] = f2bf(v);
}

// ======================= fused kernel =======================
__global__ __launch_bounds__(NT) void dsc_fused(
    const float* __restrict__ x,
    const float* __restrict__ cen_t,   // [32,3,3]
    const float* __restrict__ dir_t,   // [24,5]
    const ushort* __restrict__ Mbf,    // bf16 [128o][128c]
    const float* __restrict__ zb,      // 16B zero block
    float* __restrict__ out)
{
    __shared__ float  xs[2][XQ * 4];        // 2 x 26112 B
    __shared__ ushort yT[PIX * 128];        // 98304 B, granule-XOR swizzled
    __shared__ ushort ycp[2][CHK * YCS];    // 2 x 6272 B   (total 163328)

    const int tid = threadIdx.x;
    const int b   = blockIdx.x / NSTR;
    const int h0  = (blockIdx.x % NSTR) * RPB;
    const float* __restrict__ xb = x + (size_t)b * C_IN * HW;

    // ---- stage chunk t into xs[buf]: dest linear in quad index ----
    auto stage = [&](int t, int buf) {
        const int c0 = t * CHK;
#pragma unroll
        for (int k = 0; k < 2; ++k) {
            int d = tid + k * NT;
            if (d < XQ) {
                int q  = d % QR;
                int cr = d / QR;
                int r  = cr % XR;
                int c  = cr / XR;
                int gh = h0 - 2 + r;
                bool ok = ((unsigned)gh < (unsigned)HH) && (q < 12);
                const float* src = ok ? (xb + (size_t)(c0 + c) * HW + gh * WW + q * 4) : zb;
                __builtin_amdgcn_global_load_lds(
                    (const __attribute__((address_space(1))) unsigned int*)src,
                    (__attribute__((address_space(3))) unsigned int*)(&xs[buf][0] + (size_t)d * 4),
                    16, 0, 0);
            }
        }
    };

    // ---- dwconv chunk t: 1536 tasks, pixel pair (w0, w0+24) ----
    auto dwconv = [&](int t) {
        const int c0 = t * CHK;
        const int buf = t & 1;
        ushort* yc = ycp[buf];
#pragma unroll
        for (int k = 0; k < 2; ++k) {
            int task = tid + k * NT;
            if (task >= CHK * 192) break;
            int c   = task / 192;
            int pt  = task % 192;
            int row = pt / 24;
            int w0  = pt % 24;               // lane-stride-1 column
            int cc  = c0 + c;
            const float* xb0 = &xs[buf][(size_t)(c * XR) * XROWF];
            float a0 = 0.f, a1 = 0.f;        // pixels (row,w0), (row,w0+24)
            if (cc < 32) {                   // 3x3: x[h+i-1][w+j-1]
#pragma unroll
                for (int i = 0; i < 3; ++i) {
                    const float* xr = xb0 + (row + 1 + i) * XROWF;
                    float k0 = cen_t[cc * 9 + i * 3 + 0];
                    float k1 = cen_t[cc * 9 + i * 3 + 1];
                    float k2 = cen_t[cc * 9 + i * 3 + 2];
                    a0 += k0 * xr[(w0 - 1) & 63] + k1 * xr[w0] + k2 * xr[w0 + 1];
                    a1 += k0 * xr[w0 + 23] + k1 * xr[w0 + 24] + k2 * xr[w0 + 25];
                }
            } else if (cc < 56) {            // h: x[h][w+i-2]
                int cd = cc - 32;
                const float* xr = xb0 + (row + 2) * XROWF;
#pragma unroll
                for (int i = 0; i < 5; ++i) {
                    float tt = dir_t[cd * 5 + i];
                    a0 += tt * xr[(w0 + i - 2) & 63];
                    a1 += tt * xr[w0 + 22 + i];
                }
            } else if (cc < 80) {            // v: x[h+i-2][w]
                int cd = cc - 56;
#pragma unroll
                for (int i = 0; i < 5; ++i) {
                    float tt = dir_t[cd * 5 + i];
                    const float* xr = xb0 + (row + i) * XROWF;
                    a0 += tt * xr[w0];
                    a1 += tt * xr[w0 + 24];
                }
            } else if (cc < 104) {           // d1: x[h+i-2][w+i-2]
                int cd = cc - 80;
#pragma unroll
                for (int i = 0; i < 5; ++i) {
                    float tt = dir_t[cd * 5 + i];
                    const float* xr = xb0 + (row + i) * XROWF;
                    a0 += tt * xr[(w0 + i - 2) & 63];
                    a1 += tt * xr[w0 + 22 + i];
                }
            } else {                         // d2: x[h+i-2][w+2-i]
                int cd = cc - 104;
#pragma unroll
                for (int i = 0; i < 5; ++i) {
                    float tt = dir_t[cd * 5 + i];
                    const float* xr = xb0 + (row + i) * XROWF;
                    a0 += tt * xr[(w0 + 2 - i) & 63];
                    a1 += tt * xr[w0 + 26 - i];
                }
            }
            int p = row * 48 + w0;
            yc[c * YCS + p]      = f2bf(a0);
            yc[c * YCS + p + 24] = f2bf(a1);
        }
    };

    // ---- transpose chunk t: ycp[t&1][c][p] -> yT (granule-swizzled) ----
    auto transpose = [&](int t) {
        const ushort* src = ycp[t & 1];
#pragma unroll
        for (int k = 0; k < 2; ++k) {
            int task = tid + k * NT;
            if (task >= 1536) break;
            int cp = task & 3;
            int p  = task >> 2;
            ushort2 s;
            s.x = src[(cp * 2 + 0) * YCS + p];
            s.y = src[(cp * 2 + 1) * YCS + p];
            int gsw = t ^ (p & 7);           // granule of this chunk is t
            *(ushort2*)((char*)yT + p * 256 + (gsw << 4) + (cp << 2)) = s;
        }
    };

    // ================= channel-streamed dwconv =================
    stage(0, 0);
    __syncthreads();
    for (int t = 0; t < NCHK; ++t) {
        if (t + 1 < NCHK) stage(t + 1, (t + 1) & 1);  // DMA overlaps compute
        dwconv(t);
        if (t > 0) transpose(t - 1);
        __syncthreads();                               // drains DMA, publishes ycp
    }
    transpose(NCHK - 1);
    __syncthreads();

    // ================= MFMA mix: 16 waves, 2 passes x 64 out-ch =================
    const int l   = tid & 63;
    const int wv  = tid >> 6;                // 0..15
    const int ofr = wv & 3;                  // o-frag within 64-ch half
    const int pq  = wv >> 2;                 // p-quarter 0..3 (6 p-frags each)
    float* __restrict__ ob = out + (size_t)b * C_OUT * HW + h0 * WW;

#pragma unroll
    for (int pass = 0; pass < 2; ++pass) {
        int o0 = pass * 64 + ofr * 16;
        bf16x8 afr[4];
#pragma unroll
        for (int kb = 0; kb < 4; ++kb)
            afr[kb] = *(const bf16x8*)(Mbf + (o0 + (l & 15)) * 128 + kb * 32 + (l >> 4) * 8);
        f32x4 acc[6] = {};
#pragma unroll
        for (int kb = 0; kb < 4; ++kb) {
            int g = kb * 4 + (l >> 4);
#pragma unroll
            for (int pf = 0; pf < 6; ++pf) {
                int p = (pq * 6 + pf) * 16 + (l & 15);
                const bf16x8 bfr = *(const bf16x8*)((const char*)yT + p * 256 + ((g ^ (p & 7)) << 4));
                acc[pf] = __builtin_amdgcn_mfma_f32_16x16x32_bf16(afr[kb], bfr, acc[pf], 0, 0, 0);
            }
        }
#pragma unroll
        for (int pf = 0; pf < 6; ++pf) {
            int p = (pq * 6 + pf) * 16 + (l & 15);
            int obase = o0 + (l >> 4) * 4;
#pragma unroll
            for (int r = 0; r < 4; ++r)
                ob[(size_t)(obase + r) * HW + p] = acc[pf][r];
        }
    }
}

// ======================= launcher =======================
extern "C" void kernel_launch(void* const* d_in, const int* in_sizes, int n_in,
                              void* d_out, int out_size, void* d_ws, size_t ws_size,
                              hipStream_t stream) {
    const float* x     = (const float*)d_in[0];
    const float* cen_t = (const float*)d_in[1];
    const float* dir_t = (const float*)d_in[2];
    const float* c2c   = (const float*)d_in[3];
    const float* p2c   = (const float*)d_in[4];
    const float* d2c   = (const float*)d_in[5];
    const float* c2d   = (const float*)d_in[6];
    const float* d2dW  = (const float*)d_in[7];
    float* out = (float*)d_out;

    ushort* Mbf = (ushort*)d_ws;                       // 32 KiB
    float*  zb  = (float*)((char*)d_ws + ZB_OFF);      // 16 B zero block

    hipMemsetAsync(zb, 0, 64, stream);                 // ws is poisoned each run
    build_M<<<64, 256, 0, stream>>>(c2c, p2c, d2c, c2d, d2dW, Mbf);
    dsc_fused<<<NB * NSTR, NT, 0, stream>>>(x, cen_t, dir_t, Mbf, zb, out);
}